// Round 14
// baseline (63.100 us; speedup 1.0000x reference)
//
#include <hip/hip_runtime.h>

#define BB 16
#define CC 64
#define DD 16
#define HW 2304     // 48*48
#define HID 16
#define NEG_SLOPE 0.01f
#define CH4 9216    // float4 stride between channels at fixed (b,d)

using f4 = __attribute__((ext_vector_type(4))) float;

__device__ __forceinline__ uint2 pack_bf16x4(f4 v) {
    uint2 r;
    asm("v_cvt_pk_bf16_f32 %0, %1, %2" : "=v"(r.x) : "v"(v.x), "v"(v.y));
    asm("v_cvt_pk_bf16_f32 %0, %1, %2" : "=v"(r.y) : "v"(v.z), "v"(v.w));
    return r;
}

__device__ __forceinline__ f4 unpack_mul(uint2 p, float g) {
    f4 v;
    v.x = __uint_as_float(p.x << 16) * g;
    v.y = __uint_as_float(p.x & 0xffff0000u) * g;
    v.z = __uint_as_float(p.y << 16) * g;
    v.w = __uint_as_float(p.y & 0xffff0000u) * g;
    return v;
}

__device__ __forceinline__ void load_ch(const f4* __restrict__ p, f4 t[9]) {
    #pragma unroll
    for (int j = 0; j < 9; ++j) t[j] = p[j * 64];
}

// ch0 -> 5 reg + 4 LDS slots; ch1..3 -> 4 reg + 5 LDS slots (R7 map).
template<int I>
__device__ __forceinline__ void pack_ch(const f4 t[9], uint2 rv[17],
                                        uint2 (*stage)[1024], int tid,
                                        float& csum) {
    constexpr int nreg  = (I == 0) ? 5 : 4;
    constexpr int rbase = (I == 0) ? 0 : 5 + (I - 1) * 4;
    constexpr int lbase = (I == 0) ? 0 : 4 + (I - 1) * 5;
    float s = 0.f;
    #pragma unroll
    for (int j = 0; j < 9; ++j) {
        s += (t[j].x + t[j].y) + (t[j].z + t[j].w);
        uint2 pk = pack_bf16x4(t[j]);
        if (j < nreg) rv[rbase + j] = pk;
        else          stage[lbase + (j - nreg)][tid] = pk;
    }
    csum = s;
}

#define SB() __builtin_amdgcn_sched_barrier(0)

// R7 structure (proven best, 53.5 us) + forced load depth in phase 1:
//  - __launch_bounds__(1024, 4): 4 waves/EU = our exact occupancy, raises the
//    VGPR cap to 128 (R13's waves_per_eu attribute did NOT move it).
//  - sched_barrier(0)-pinned batches: ch0+ch1 loads (72 VGPR of dests) issue
//    before any pack consumes them; ch2/ch3 loads issue between packs. In-order
//    vmcnt return then keeps ~18 loads/lane outstanding through the read phase
//    (R7's 64-VGPR budget allowed ~5).
__global__ __launch_bounds__(1024, 4) void fused_se_kernel(
    const float* __restrict__ x,
    const float* __restrict__ w1, const float* __restrict__ b1,
    const float* __restrict__ w2, const float* __restrict__ b2,
    float* __restrict__ out)
{
    const int bd   = blockIdx.x;
    const int b    = bd >> 4;
    const int d    = bd & 15;
    const int tid  = threadIdx.x;
    const int wave = tid >> 6;
    const int lane = tid & 63;

    __shared__ uint2 stage[19][1024];      // 155,648 B
    __shared__ float pooled[CC];
    __shared__ float hbuf[HID];
    __shared__ float gate_s[CC];

    const size_t base4 = ((size_t)(b * CC) * DD + d) * (HW / 4);
    const f4* xb = (const f4*)x + base4 + lane;

    uint2 rv[17];
    float csum[4];

    // ---- Phase 1: deep-pipelined read + pool + pack ----
    {
        f4 t0[9], t1[9], t2[9], t3[9];
        load_ch(xb + (size_t)(wave * 4 + 0) * CH4, t0);
        load_ch(xb + (size_t)(wave * 4 + 1) * CH4, t1);
        SB();                                   // 18 loads in flight
        load_ch(xb + (size_t)(wave * 4 + 2) * CH4, t2);
        SB();                                   // 27 in flight
        pack_ch<0>(t0, rv, stage, tid, csum[0]);   // waits t0 only (vmcnt 18)
        SB();
        load_ch(xb + (size_t)(wave * 4 + 3) * CH4, t3);
        SB();
        pack_ch<1>(t1, rv, stage, tid, csum[1]);
        pack_ch<2>(t2, rv, stage, tid, csum[2]);
        pack_ch<3>(t3, rv, stage, tid, csum[3]);
    }

    // batched shuffle reduces (4-way ILP)
    #pragma unroll
    for (int m = 32; m; m >>= 1) {
        #pragma unroll
        for (int i = 0; i < 4; ++i) csum[i] += __shfl_xor(csum[i], m, 64);
    }
    if (lane == 0) {
        #pragma unroll
        for (int i = 0; i < 4; ++i) pooled[wave * 4 + i] = csum[i] * (1.0f / HW);
    }
    __syncthreads();

    // ---- Phase 2: tiny MLP (wave-parallel layer 1) ----
    {
        float v = w1[wave * CC + lane] * pooled[lane];
        #pragma unroll
        for (int m = 32; m; m >>= 1) v += __shfl_xor(v, m, 64);
        if (lane == 0) {
            float acc = v + b1[wave];
            hbuf[wave] = acc >= 0.f ? acc : NEG_SLOPE * acc;
        }
    }
    __syncthreads();
    if (tid < CC) {
        float acc = b2[tid];
        #pragma unroll
        for (int o = 0; o < HID; ++o) acc += w2[tid * HID + o] * hbuf[o];
        gate_s[tid] = 1.0f / (1.0f + expf(-acc));
    }
    __syncthreads();

    // ---- Phase 3: unpack, multiply, NT store ----
    f4* ob = (f4*)out + base4 + lane;
    #pragma unroll
    for (int i = 0; i < 4; ++i) {
        const float gv = gate_s[wave * 4 + i];
        f4* q = ob + (size_t)(wave * 4 + i) * CH4;
        const int nreg  = (i == 0) ? 5 : 4;
        const int rbase = (i == 0) ? 0 : 5 + (i - 1) * 4;
        const int lbase = (i == 0) ? 0 : 4 + (i - 1) * 5;
        #pragma unroll
        for (int j = 0; j < 9; ++j) {
            uint2 pk = (j < nreg) ? rv[rbase + j] : stage[lbase + (j - nreg)][tid];
            __builtin_nontemporal_store(unpack_mul(pk, gv), q + j * 64);
        }
    }
}

extern "C" void kernel_launch(void* const* d_in, const int* in_sizes, int n_in,
                              void* d_out, int out_size, void* d_ws, size_t ws_size,
                              hipStream_t stream) {
    const float* x  = (const float*)d_in[0];
    const float* w1 = (const float*)d_in[1];
    const float* b1 = (const float*)d_in[2];
    const float* w2 = (const float*)d_in[3];
    const float* b2 = (const float*)d_in[4];
    float* out = (float*)d_out;

    fused_se_kernel<<<BB * DD, 1024, 0, stream>>>(x, w1, b1, w2, b2, out);
}

// Round 15
// 62.635 us; speedup vs baseline: 1.0074x; 1.0074x over previous
//
#include <hip/hip_runtime.h>

#define BB 16
#define CC 64
#define DD 16
#define HW 2304     // 48*48
#define HID 16
#define NEG_SLOPE 0.01f
#define CH4 9216    // float4 stride between channels at fixed (b,d)

using f4 = __attribute__((ext_vector_type(4))) float;

__device__ __forceinline__ uint2 pack_bf16x4(f4 v) {
    uint2 r;
    asm("v_cvt_pk_bf16_f32 %0, %1, %2" : "=v"(r.x) : "v"(v.x), "v"(v.y));
    asm("v_cvt_pk_bf16_f32 %0, %1, %2" : "=v"(r.y) : "v"(v.z), "v"(v.w));
    return r;
}

__device__ __forceinline__ f4 unpack_mul(uint2 p, float g) {
    f4 v;
    v.x = __uint_as_float(p.x << 16) * g;
    v.y = __uint_as_float(p.x & 0xffff0000u) * g;
    v.z = __uint_as_float(p.y << 16) * g;
    v.w = __uint_as_float(p.y & 0xffff0000u) * g;
    return v;
}

__device__ __forceinline__ void load_ch(const f4* __restrict__ p, f4 t[9]) {
    #pragma unroll
    for (int j = 0; j < 9; ++j) t[j] = p[j * 64];
}

// ch0 -> 5 reg + 4 LDS slots; ch1..3 -> 4 reg + 5 LDS slots (R7 map).
template<int I>
__device__ __forceinline__ void pack_ch(const f4 t[9], uint2 rv[17],
                                        uint2 (*stage)[1024], int tid,
                                        float& csum) {
    constexpr int nreg  = (I == 0) ? 5 : 4;
    constexpr int rbase = (I == 0) ? 0 : 5 + (I - 1) * 4;
    constexpr int lbase = (I == 0) ? 0 : 4 + (I - 1) * 5;
    float s = 0.f;
    #pragma unroll
    for (int j = 0; j < 9; ++j) {
        s += (t[j].x + t[j].y) + (t[j].z + t[j].w);
        uint2 pk = pack_bf16x4(t[j]);
        if (j < nreg) rv[rbase + j] = pk;
        else          stage[lbase + (j - nreg)][tid] = pk;
    }
    csum = s;
}

#define SB() __builtin_amdgcn_sched_barrier(0)

// R7 structure (proven best, 53.5 us) + forced load depth in phase 1:
//  - __launch_bounds__(1024, 4): 4 waves/EU = our exact occupancy, raises the
//    VGPR cap to 128 (R13's waves_per_eu attribute did NOT move it).
//  - sched_barrier(0)-pinned batches: ch0+ch1 loads (72 VGPR of dests) issue
//    before any pack consumes them; ch2/ch3 loads issue between packs. In-order
//    vmcnt return then keeps ~18 loads/lane outstanding through the read phase
//    (R7's 64-VGPR budget allowed ~5).
__global__ __launch_bounds__(1024, 4) void fused_se_kernel(
    const float* __restrict__ x,
    const float* __restrict__ w1, const float* __restrict__ b1,
    const float* __restrict__ w2, const float* __restrict__ b2,
    float* __restrict__ out)
{
    const int bd   = blockIdx.x;
    const int b    = bd >> 4;
    const int d    = bd & 15;
    const int tid  = threadIdx.x;
    const int wave = tid >> 6;
    const int lane = tid & 63;

    __shared__ uint2 stage[19][1024];      // 155,648 B
    __shared__ float pooled[CC];
    __shared__ float hbuf[HID];
    __shared__ float gate_s[CC];

    const size_t base4 = ((size_t)(b * CC) * DD + d) * (HW / 4);
    const f4* xb = (const f4*)x + base4 + lane;

    uint2 rv[17];
    float csum[4];

    // ---- Phase 1: deep-pipelined read + pool + pack ----
    {
        f4 t0[9], t1[9], t2[9], t3[9];
        load_ch(xb + (size_t)(wave * 4 + 0) * CH4, t0);
        load_ch(xb + (size_t)(wave * 4 + 1) * CH4, t1);
        SB();                                   // 18 loads in flight
        load_ch(xb + (size_t)(wave * 4 + 2) * CH4, t2);
        SB();                                   // 27 in flight
        pack_ch<0>(t0, rv, stage, tid, csum[0]);   // waits t0 only (vmcnt 18)
        SB();
        load_ch(xb + (size_t)(wave * 4 + 3) * CH4, t3);
        SB();
        pack_ch<1>(t1, rv, stage, tid, csum[1]);
        pack_ch<2>(t2, rv, stage, tid, csum[2]);
        pack_ch<3>(t3, rv, stage, tid, csum[3]);
    }

    // batched shuffle reduces (4-way ILP)
    #pragma unroll
    for (int m = 32; m; m >>= 1) {
        #pragma unroll
        for (int i = 0; i < 4; ++i) csum[i] += __shfl_xor(csum[i], m, 64);
    }
    if (lane == 0) {
        #pragma unroll
        for (int i = 0; i < 4; ++i) pooled[wave * 4 + i] = csum[i] * (1.0f / HW);
    }
    __syncthreads();

    // ---- Phase 2: tiny MLP (wave-parallel layer 1) ----
    {
        float v = w1[wave * CC + lane] * pooled[lane];
        #pragma unroll
        for (int m = 32; m; m >>= 1) v += __shfl_xor(v, m, 64);
        if (lane == 0) {
            float acc = v + b1[wave];
            hbuf[wave] = acc >= 0.f ? acc : NEG_SLOPE * acc;
        }
    }
    __syncthreads();
    if (tid < CC) {
        float acc = b2[tid];
        #pragma unroll
        for (int o = 0; o < HID; ++o) acc += w2[tid * HID + o] * hbuf[o];
        gate_s[tid] = 1.0f / (1.0f + expf(-acc));
    }
    __syncthreads();

    // ---- Phase 3: unpack, multiply, NT store ----
    f4* ob = (f4*)out + base4 + lane;
    #pragma unroll
    for (int i = 0; i < 4; ++i) {
        const float gv = gate_s[wave * 4 + i];
        f4* q = ob + (size_t)(wave * 4 + i) * CH4;
        const int nreg  = (i == 0) ? 5 : 4;
        const int rbase = (i == 0) ? 0 : 5 + (i - 1) * 4;
        const int lbase = (i == 0) ? 0 : 4 + (i - 1) * 5;
        #pragma unroll
        for (int j = 0; j < 9; ++j) {
            uint2 pk = (j < nreg) ? rv[rbase + j] : stage[lbase + (j - nreg)][tid];
            __builtin_nontemporal_store(unpack_mul(pk, gv), q + j * 64);
        }
    }
}

extern "C" void kernel_launch(void* const* d_in, const int* in_sizes, int n_in,
                              void* d_out, int out_size, void* d_ws, size_t ws_size,
                              hipStream_t stream) {
    const float* x  = (const float*)d_in[0];
    const float* w1 = (const float*)d_in[1];
    const float* b1 = (const float*)d_in[2];
    const float* w2 = (const float*)d_in[3];
    const float* b2 = (const float*)d_in[4];
    float* out = (float*)d_out;

    fused_se_kernel<<<BB * DD, 1024, 0, stream>>>(x, w1, b1, w2, b2, out);
}